// Round 1
// baseline (263.947 us; speedup 1.0000x reference)
//
#include <hip/hip_runtime.h>
#include <math.h>

#define NN 102400
#define D 256
#define B 2048
#define MT 64     // nodes per block in k_attn_e
#define KT 32     // k tile

// K0: seg_start[b] = lower_bound(seg_ids, b); seg_start[B] = NN
__global__ void k_bounds(const int* __restrict__ seg, int* __restrict__ seg_start) {
    int b = blockIdx.x * blockDim.x + threadIdx.x;
    if (b > B) return;
    int lo = 0, hi = NN;
    while (lo < hi) { int mid = (lo + hi) >> 1; if (seg[mid] < b) lo = mid + 1; else hi = mid; }
    seg_start[b] = lo;
}

// K1: anchor (segment mean) -> out[:, 256:512]
__global__ void k_anchor(const float* __restrict__ ifeat, const int* __restrict__ seg_start,
                         float* __restrict__ out) {
    int b = blockIdx.x;
    int t = threadIdx.x; // 256 threads, thread = column
    int s = seg_start[b], e = seg_start[b + 1];
    float a0 = 0.f, a1 = 0.f, a2 = 0.f, a3 = 0.f;
    int i = s;
    for (; i + 4 <= e; i += 4) {
        a0 += ifeat[(size_t)(i + 0) * D + t];
        a1 += ifeat[(size_t)(i + 1) * D + t];
        a2 += ifeat[(size_t)(i + 2) * D + t];
        a3 += ifeat[(size_t)(i + 3) * D + t];
    }
    for (; i < e; ++i) a0 += ifeat[(size_t)i * D + t];
    float sum = (a0 + a1) + (a2 + a3);
    int cnt = e - s;
    float inv = 1.0f / (float)(cnt > 0 ? cnt : 1);
    out[(size_t)b * 512 + 256 + t] = sum * inv;
}

// K2: feat_v = anchor @ Wv^T + bv, 16 segments per block
__global__ void k_featv(const float* __restrict__ out, const float* __restrict__ Wv,
                        const float* __restrict__ bv, float* __restrict__ feat_v) {
    __shared__ float anc[16][D];
    int b0 = blockIdx.x * 16;
    int t = threadIdx.x; // 256, thread = output column j
#pragma unroll
    for (int r = 0; r < 16; ++r) anc[r][t] = out[(size_t)(b0 + r) * 512 + 256 + t];
    __syncthreads();
    float acc[16];
#pragma unroll
    for (int s = 0; s < 16; ++s) acc[s] = 0.f;
    const float* wrow = Wv + (size_t)t * D;
    for (int k = 0; k < D; k += 4) {
        float4 w = *(const float4*)(wrow + k);
#pragma unroll
        for (int s = 0; s < 16; ++s) {
            acc[s] += anc[s][k] * w.x + anc[s][k + 1] * w.y
                    + anc[s][k + 2] * w.z + anc[s][k + 3] * w.w;
        }
    }
    float bj = bv[t];
#pragma unroll
    for (int s = 0; s < 16; ++s) feat_v[(size_t)(b0 + s) * D + t] = acc[s] + bj;
}

// K3: e[n] = we . sigmoid(ifeat[n] @ Wu^T + feat_v[seg[n]])
// block: 512 threads, 64 nodes, all 256 j. LDS-tiled fp32 GEMM + fused reduce.
__global__ __launch_bounds__(512)
void k_attn_e(const float* __restrict__ ifeat, const float* __restrict__ Wu,
              const float* __restrict__ feat_v, const float* __restrict__ we,
              const int* __restrict__ seg_ids, float* __restrict__ e_out) {
    __shared__ float As[KT][MT];   // [k][node]  8 KB (A-read is wave broadcast)
    __shared__ float Bs[KT][D];    // [k][j]    32 KB (B-read is contiguous wave b128)
    int tx = threadIdx.x;
    int jg = tx & 63;              // j-group: j = jg*4 .. +3 (spans a wave)
    int ng = tx >> 6;              // node-group == wave id: nodes ng*8 .. +7
    int nbase = blockIdx.x * MT;

    float acc[8][4];
#pragma unroll
    for (int n = 0; n < 8; ++n)
#pragma unroll
        for (int c = 0; c < 4; ++c) acc[n][c] = 0.f;

    int an = tx >> 3;              // staging: node 0..63
    int akq = tx & 7;              // staging: float4 index along k
    int bj = tx >> 1;              // staging: j 0..255
    int bh = tx & 1;               // staging: which 16-k half

    for (int k0 = 0; k0 < D; k0 += KT) {
        __syncthreads();
        // stage A (transposed)
        float4 av = *(const float4*)(ifeat + (size_t)(nbase + an) * D + k0 + akq * 4);
        As[akq * 4 + 0][an] = av.x;
        As[akq * 4 + 1][an] = av.y;
        As[akq * 4 + 2][an] = av.z;
        As[akq * 4 + 3][an] = av.w;
        // stage B (transposed): Wu row bj, k = k0 + bh*16 .. +15
        const float* wp = Wu + (size_t)bj * D + k0 + bh * 16;
#pragma unroll
        for (int q = 0; q < 4; ++q) {
            float4 wv = *(const float4*)(wp + q * 4);
            int kk = bh * 16 + q * 4;
            Bs[kk + 0][bj] = wv.x;
            Bs[kk + 1][bj] = wv.y;
            Bs[kk + 2][bj] = wv.z;
            Bs[kk + 3][bj] = wv.w;
        }
        __syncthreads();
#pragma unroll
        for (int kk = 0; kk < KT; ++kk) {
            float4 a0 = *(const float4*)&As[kk][ng * 8];
            float4 a1 = *(const float4*)&As[kk][ng * 8 + 4];
            float4 bq = *(const float4*)&Bs[kk][jg * 4];
            float av8[8] = {a0.x, a0.y, a0.z, a0.w, a1.x, a1.y, a1.z, a1.w};
            float bv4[4] = {bq.x, bq.y, bq.z, bq.w};
#pragma unroll
            for (int n = 0; n < 8; ++n)
#pragma unroll
                for (int c = 0; c < 4; ++c)
                    acc[n][c] += av8[n] * bv4[c];
        }
    }

    // epilogue: sigmoid, dot with we, wave-reduce over the 64 j-groups
    float wej[4];
    const float* wep = we + jg * 4;
#pragma unroll
    for (int c = 0; c < 4; ++c) wej[c] = wep[c];

    float part[8];
#pragma unroll
    for (int n = 0; n < 8; ++n) {
        int node = nbase + ng * 8 + n;
        int sg = seg_ids[node];
        const float* fv = feat_v + (size_t)sg * D + jg * 4;
        float p = 0.f;
#pragma unroll
        for (int c = 0; c < 4; ++c) {
            float u = acc[n][c] + fv[c];
            float s = 1.0f / (1.0f + __expf(-u));
            p += s * wej[c];
        }
        part[n] = p;
    }
#pragma unroll
    for (int off = 32; off >= 1; off >>= 1) {
#pragma unroll
        for (int n = 0; n < 8; ++n) part[n] += __shfl_xor(part[n], off, 64);
    }
    if (jg == 0) {
#pragma unroll
        for (int n = 0; n < 8; ++n) e_out[nbase + ng * 8 + n] = part[n];
    }
}

// K4: segment softmax (max, denom) + alpha-weighted segment sum -> out[:, 0:256]
__global__ void k_softmax_rst(const float* __restrict__ ifeat, const int* __restrict__ seg_start,
                              const float* __restrict__ e, float* __restrict__ out) {
    int b = blockIdx.x;
    int t = threadIdx.x; // 256
    int s = seg_start[b], en = seg_start[b + 1];
    // phase 1: segment max
    float m = -1e30f;
    for (int i = s + t; i < en; i += 256) m = fmaxf(m, e[i]);
#pragma unroll
    for (int off = 32; off >= 1; off >>= 1) m = fmaxf(m, __shfl_xor(m, off, 64));
    __shared__ float red[4];
    if ((t & 63) == 0) red[t >> 6] = m;
    __syncthreads();
    float mall = fmaxf(fmaxf(red[0], red[1]), fmaxf(red[2], red[3]));
    // phase 2: denom
    float dsum = 0.f;
    for (int i = s + t; i < en; i += 256) dsum += __expf(e[i] - mall);
#pragma unroll
    for (int off = 32; off >= 1; off >>= 1) dsum += __shfl_xor(dsum, off, 64);
    __shared__ float red2[4];
    if ((t & 63) == 0) red2[t >> 6] = dsum;
    __syncthreads();
    float denom = red2[0] + red2[1] + red2[2] + red2[3];
    float invd = (en > s) ? 1.0f / denom : 0.f;
    // phase 3: weighted column sum, thread = column
    float acc = 0.f;
    for (int i = s; i < en; ++i) {
        float alpha = __expf(e[i] - mall) * invd;
        acc += ifeat[(size_t)i * D + t] * alpha;
    }
    out[(size_t)b * 512 + t] = acc;
}

extern "C" void kernel_launch(void* const* d_in, const int* in_sizes, int n_in,
                              void* d_out, int out_size, void* d_ws, size_t ws_size,
                              hipStream_t stream) {
    const float* ifeat = (const float*)d_in[0];
    const float* Wu    = (const float*)d_in[1];
    const float* Wv    = (const float*)d_in[2];
    const float* bv    = (const float*)d_in[3];
    const float* we    = (const float*)d_in[4];
    const int*   seg   = (const int*)d_in[5];
    float* out = (float*)d_out;

    char* ws = (char*)d_ws;
    int*   seg_start = (int*)ws;                                   // (B+1) ints
    float* feat_v    = (float*)(ws + 16384);                       // B*D floats (2 MB)
    float* e_buf     = (float*)(ws + 16384 + (size_t)B * D * 4);   // NN floats (400 KB)

    k_bounds<<<(B + 1 + 255) / 256, 256, 0, stream>>>(seg, seg_start);
    k_anchor<<<B, 256, 0, stream>>>(ifeat, seg_start, out);
    k_featv<<<B / 16, 256, 0, stream>>>(out, Wv, bv, feat_v);
    k_attn_e<<<NN / MT, 512, 0, stream>>>(ifeat, Wu, feat_v, we, seg, e_buf);
    k_softmax_rst<<<B, 256, 0, stream>>>(ifeat, seg_start, e_buf, out);
}

// Round 2
// 155.074 us; speedup vs baseline: 1.7021x; 1.7021x over previous
//
#include <hip/hip_runtime.h>
#include <math.h>

#define NN 102400
#define D 256
#define B 2048
#define STR 40   // LDS row stride in bf16 (80 B = 5x16B: aligned, 2-way banks = free)

typedef __bf16 bf16x8 __attribute__((ext_vector_type(8)));
typedef float f32x4 __attribute__((ext_vector_type(4)));

// K0: seg_start[b] = lower_bound(seg_ids, b); seg_start[B] = NN
__global__ void k_bounds(const int* __restrict__ seg, int* __restrict__ seg_start) {
    int b = blockIdx.x * blockDim.x + threadIdx.x;
    if (b > B) return;
    int lo = 0, hi = NN;
    while (lo < hi) { int mid = (lo + hi) >> 1; if (seg[mid] < b) lo = mid + 1; else hi = mid; }
    seg_start[b] = lo;
}

// K1: anchor (segment mean) -> out[:, 256:512]
__global__ void k_anchor(const float* __restrict__ ifeat, const int* __restrict__ seg_start,
                         float* __restrict__ out) {
    int b = blockIdx.x;
    int t = threadIdx.x; // 256 threads, thread = column
    int s = seg_start[b], e = seg_start[b + 1];
    float a0 = 0.f, a1 = 0.f, a2 = 0.f, a3 = 0.f;
    int i = s;
    for (; i + 4 <= e; i += 4) {
        a0 += ifeat[(size_t)(i + 0) * D + t];
        a1 += ifeat[(size_t)(i + 1) * D + t];
        a2 += ifeat[(size_t)(i + 2) * D + t];
        a3 += ifeat[(size_t)(i + 3) * D + t];
    }
    for (; i < e; ++i) a0 += ifeat[(size_t)i * D + t];
    float sum = (a0 + a1) + (a2 + a3);
    int cnt = e - s;
    float inv = 1.0f / (float)(cnt > 0 ? cnt : 1);
    out[(size_t)b * 512 + 256 + t] = sum * inv;
}

// K2: feat_v = anchor @ Wv^T + bv, 16 segments per block
__global__ void k_featv(const float* __restrict__ out, const float* __restrict__ Wv,
                        const float* __restrict__ bv, float* __restrict__ feat_v) {
    __shared__ float anc[16][D];
    int b0 = blockIdx.x * 16;
    int t = threadIdx.x; // 256, thread = output column j
#pragma unroll
    for (int r = 0; r < 16; ++r) anc[r][t] = out[(size_t)(b0 + r) * 512 + 256 + t];
    __syncthreads();
    float acc[16];
#pragma unroll
    for (int s = 0; s < 16; ++s) acc[s] = 0.f;
    const float* wrow = Wv + (size_t)t * D;
    for (int k = 0; k < D; k += 4) {
        float4 w = *(const float4*)(wrow + k);
#pragma unroll
        for (int s = 0; s < 16; ++s) {
            acc[s] += anc[s][k] * w.x + anc[s][k + 1] * w.y
                    + anc[s][k + 2] * w.z + anc[s][k + 3] * w.w;
        }
    }
    float bj = bv[t];
#pragma unroll
    for (int s = 0; s < 16; ++s) feat_v[(size_t)(b0 + s) * D + t] = acc[s] + bj;
}

// K3 (MFMA): e[n] = we . sigmoid(bf16(ifeat[n]) @ bf16(Wu)^T + feat_v[seg[n]])
// block: 256 threads = 4 waves in 2x2 over (64 nodes x 256 j). K-chunks of 32.
// wave (wr,wc): rows [wr*32, wr*32+32) x cols [wc*128, wc*128+128)
//   = 2 row-tiles x 8 col-tiles of 16x16x32 MFMA, acc = 16 tiles x f32x4 = 64 VGPR.
__global__ __launch_bounds__(256, 4)
void k_attn_e_mfma(const float* __restrict__ ifeat, const float* __restrict__ Wu,
                   const float* __restrict__ feat_v, const float* __restrict__ we,
                   const int* __restrict__ seg_ids, float* __restrict__ e_out) {
    __shared__ __bf16 As[64 * STR];    // 5120 B
    __shared__ __bf16 Bs[256 * STR];   // 20480 B
    __shared__ float  ered[64][2];

    int tx = threadIdx.x;
    int lane = tx & 63;
    int w  = tx >> 6;
    int wr = w >> 1;     // row half (32 rows)
    int wc = w & 1;      // col half (128 cols)
    int nbase = blockIdx.x * 64;

    f32x4 acc[2][8];
#pragma unroll
    for (int rt = 0; rt < 2; ++rt)
#pragma unroll
        for (int ct = 0; ct < 8; ++ct) acc[rt][ct] = (f32x4){0.f, 0.f, 0.f, 0.f};

    int ln15 = lane & 15;
    int lg   = lane >> 4;

    // staging maps: A: thread -> (row 0..63, quarter 0..3) ; B: thread -> Wu row tx
    int ar = tx >> 2, aq = tx & 3;

    for (int k0 = 0; k0 < D; k0 += 32) {
        __syncthreads();
        // ---- stage A: 64x32 fp32 -> bf16 LDS ----
        {
            const float* ap = ifeat + (size_t)(nbase + ar) * D + k0 + aq * 8;
            float4 a0 = *(const float4*)(ap);
            float4 a1 = *(const float4*)(ap + 4);
            bf16x8 v;
            v[0] = (__bf16)a0.x; v[1] = (__bf16)a0.y; v[2] = (__bf16)a0.z; v[3] = (__bf16)a0.w;
            v[4] = (__bf16)a1.x; v[5] = (__bf16)a1.y; v[6] = (__bf16)a1.z; v[7] = (__bf16)a1.w;
            *(bf16x8*)&As[ar * STR + aq * 8] = v;
        }
        // ---- stage B: Wu rows (all 256 j) x 32 k -> bf16 LDS; thread = j row ----
        {
            const float* wp = Wu + (size_t)tx * D + k0;
#pragma unroll
            for (int h = 0; h < 4; ++h) {
                float4 b0 = *(const float4*)(wp + h * 8);
                float4 b1 = *(const float4*)(wp + h * 8 + 4);
                bf16x8 v;
                v[0] = (__bf16)b0.x; v[1] = (__bf16)b0.y; v[2] = (__bf16)b0.z; v[3] = (__bf16)b0.w;
                v[4] = (__bf16)b1.x; v[5] = (__bf16)b1.y; v[6] = (__bf16)b1.z; v[7] = (__bf16)b1.w;
                *(bf16x8*)&Bs[tx * STR + h * 8] = v;
            }
        }
        __syncthreads();
        // ---- fragments + MFMA ----
        bf16x8 af[2];
#pragma unroll
        for (int rt = 0; rt < 2; ++rt)
            af[rt] = *(const bf16x8*)&As[(wr * 32 + rt * 16 + ln15) * STR + lg * 8];
#pragma unroll
        for (int ct = 0; ct < 8; ++ct) {
            bf16x8 bf = *(const bf16x8*)&Bs[(wc * 128 + ct * 16 + ln15) * STR + lg * 8];
            acc[0][ct] = __builtin_amdgcn_mfma_f32_16x16x32_bf16(af[0], bf, acc[0][ct], 0, 0, 0);
            acc[1][ct] = __builtin_amdgcn_mfma_f32_16x16x32_bf16(af[1], bf, acc[1][ct], 0, 0, 0);
        }
    }

    // ---- epilogue: u = acc + feat_v[seg[row]][col]; p += we[col]*sigmoid(u); reduce ----
    float wev[8];
#pragma unroll
    for (int ct = 0; ct < 8; ++ct) wev[ct] = we[wc * 128 + ct * 16 + ln15];

    float part[2][4];
#pragma unroll
    for (int rt = 0; rt < 2; ++rt) {
#pragma unroll
        for (int r = 0; r < 4; ++r) {
            int row = nbase + wr * 32 + rt * 16 + lg * 4 + r;
            int sg = seg_ids[row];
            const float* fv = feat_v + (size_t)sg * D + wc * 128;
            float p = 0.f;
#pragma unroll
            for (int ct = 0; ct < 8; ++ct) {
                float u = acc[rt][ct][r] + fv[ct * 16 + ln15];
                p += wev[ct] / (1.0f + __expf(-u));
            }
            part[rt][r] = p;
        }
    }
#pragma unroll
    for (int off = 8; off >= 1; off >>= 1) {
#pragma unroll
        for (int rt = 0; rt < 2; ++rt)
#pragma unroll
            for (int r = 0; r < 4; ++r)
                part[rt][r] += __shfl_xor(part[rt][r], off, 64);
    }
    if (ln15 == 0) {
#pragma unroll
        for (int rt = 0; rt < 2; ++rt)
#pragma unroll
            for (int r = 0; r < 4; ++r)
                ered[wr * 32 + rt * 16 + lg * 4 + r][wc] = part[rt][r];
    }
    __syncthreads();
    if (tx < 64) e_out[nbase + tx] = ered[tx][0] + ered[tx][1];
}

// K4: segment softmax (max, denom) + alpha-weighted segment sum -> out[:, 0:256]
__global__ void k_softmax_rst(const float* __restrict__ ifeat, const int* __restrict__ seg_start,
                              const float* __restrict__ e, float* __restrict__ out) {
    int b = blockIdx.x;
    int t = threadIdx.x; // 256
    int s = seg_start[b], en = seg_start[b + 1];
    float m = -1e30f;
    for (int i = s + t; i < en; i += 256) m = fmaxf(m, e[i]);
#pragma unroll
    for (int off = 32; off >= 1; off >>= 1) m = fmaxf(m, __shfl_xor(m, off, 64));
    __shared__ float red[4];
    if ((t & 63) == 0) red[t >> 6] = m;
    __syncthreads();
    float mall = fmaxf(fmaxf(red[0], red[1]), fmaxf(red[2], red[3]));
    float dsum = 0.f;
    for (int i = s + t; i < en; i += 256) dsum += __expf(e[i] - mall);
#pragma unroll
    for (int off = 32; off >= 1; off >>= 1) dsum += __shfl_xor(dsum, off, 64);
    __shared__ float red2[4];
    if ((t & 63) == 0) red2[t >> 6] = dsum;
    __syncthreads();
    float denom = red2[0] + red2[1] + red2[2] + red2[3];
    float invd = (en > s) ? 1.0f / denom : 0.f;
    float acc = 0.f;
    for (int i = s; i < en; ++i) {
        float alpha = __expf(e[i] - mall) * invd;
        acc += ifeat[(size_t)i * D + t] * alpha;
    }
    out[(size_t)b * 512 + t] = acc;
}

extern "C" void kernel_launch(void* const* d_in, const int* in_sizes, int n_in,
                              void* d_out, int out_size, void* d_ws, size_t ws_size,
                              hipStream_t stream) {
    const float* ifeat = (const float*)d_in[0];
    const float* Wu    = (const float*)d_in[1];
    const float* Wv    = (const float*)d_in[2];
    const float* bv    = (const float*)d_in[3];
    const float* we    = (const float*)d_in[4];
    const int*   seg   = (const int*)d_in[5];
    float* out = (float*)d_out;

    char* ws = (char*)d_ws;
    int*   seg_start = (int*)ws;                                   // (B+1) ints
    float* feat_v    = (float*)(ws + 16384);                       // B*D floats (2 MB)
    float* e_buf     = (float*)(ws + 16384 + (size_t)B * D * 4);   // NN floats (400 KB)

    k_bounds<<<(B + 1 + 255) / 256, 256, 0, stream>>>(seg, seg_start);
    k_anchor<<<B, 256, 0, stream>>>(ifeat, seg_start, out);
    k_featv<<<B / 16, 256, 0, stream>>>(out, Wv, bv, feat_v);
    k_attn_e_mfma<<<NN / 64, 256, 0, stream>>>(ifeat, Wu, feat_v, we, seg, e_buf);
    k_softmax_rst<<<B, 256, 0, stream>>>(ifeat, seg_start, e_buf, out);
}